// Round 12
// baseline (256.232 us; speedup 1.0000x reference)
//
#include <hip/hip_runtime.h>

// DmvCell RNN scan, B=32, T=2048, D=512. out[b][t] = [mean|var|max] (3*D).
// Compulsory: 128 MB in + 402 MB nt-out.
// Proven: nt stores + regular loads (R4/R5/R10 2x2), 2-kernel agg->scan
// (R8/R11 = 118.7us), coop fold, D-split scan.
// Falsified: fine-grained lookback (R7), NC=128 (R9), occupancy as main
// lever (R2/R9/R11), fold traffic (R8), rw batching (R8).
//
// R12: cooperative SINGLE kernel, role-split blocks, COARSE per-b handoff:
//  - 128 agg-role blocks x 4 items in ascending-b phases (b 0-7, 8-15,
//    16-23, 24-31); per item: table write, __threadfence, one atomicAdd
//    cnt[b] per block.
//  - 1024 scan-role blocks (b, chunk-group g, D-half h; 4 waves = 4 chunks):
//    lane 0 spins on cnt[b]==16 (s_sleep), acquire fence, then R11's proven
//    fold + rescan + nt stores.
//  Coop launch => all 1152 blocks co-resident => no deadlock. Early-b scan
//  blocks start writing while late-b agg still reads -> R/W overlap that the
//  kernel boundary serialized. Sync cost ~1000x coarser than R7's.

#define BB 32
#define TT 2048
#define DD 512
#define NCHAIN (BB * DD)
#define NAGG 128

typedef float f32x4 __attribute__((ext_vector_type(4)));

__device__ __forceinline__ float fast_rcp(float x) {
#if __has_builtin(__builtin_amdgcn_rcpf)
    return __builtin_amdgcn_rcpf(x);
#else
    return 1.0f / x;
#endif
}

__device__ __forceinline__ f32x4 vmax4(f32x4 a, f32x4 b) {
#if __has_builtin(__builtin_elementwise_max)
    return __builtin_elementwise_max(a, b);
#else
    f32x4 r;
    r.x = fmaxf(a.x, b.x); r.y = fmaxf(a.y, b.y);
    r.z = fmaxf(a.z, b.z); r.w = fmaxf(a.w, b.w);
    return r;
#endif
}

__device__ __forceinline__ void nts(f32x4 v, float* p) {
#if __has_builtin(__builtin_nontemporal_store)
    __builtin_nontemporal_store(v, (f32x4*)p);
#else
    *(f32x4*)p = v;
#endif
}

struct St1 { float n; f32x4 s, m2, mx; };

__device__ __forceinline__ void st1_zero(St1& r) {
    r.n = 0.f;
    r.s = r.m2 = r.mx = (f32x4){0.f, 0.f, 0.f, 0.f};
}

__device__ __forceinline__ void st1_merge(St1& r, float tn, float itn,
                                          f32x4 ts, f32x4 tm, f32x4 tx) {
    if (r.n == 0.f) {
        r.n = tn; r.s = ts; r.m2 = tm; r.mx = tx;
    } else {
        float n     = r.n + tn;
        float irn   = fast_rcp(r.n);
        float scale = r.n * tn * fast_rcp(n);
        f32x4 da = ts * itn - r.s * irn;
        r.m2 += tm + da * da * scale;
        r.s += ts;
        r.mx = vmax4(r.mx, tx);
        r.n = n;
    }
}

// ================= R12 fused cooperative kernel ===========================
template <int NC>
__launch_bounds__(256, 6)
__global__ void dmv_fused(const float* __restrict__ x,
                          f32x4* __restrict__ ws4,
                          int* __restrict__ cnt,
                          float* __restrict__ out) {
    constexpr int CHUNK = TT / NC;       // 32
    constexpr int GRP   = NC / 4;        // 16 chunk-groups per b
    f32x4* __restrict__ aS  = ws4;
    f32x4* __restrict__ aM2 = ws4 + (size_t)NC * 4096;
    f32x4* __restrict__ aMX = ws4 + 2 * (size_t)NC * 4096;
    constexpr float icf = 1.0f / (float)CHUNK;

    __shared__ f32x4 part[4][3][64];

    const int tid = threadIdx.x;
    const int w   = tid >> 6;
    const int l   = tid & 63;

    if (blockIdx.x < NAGG) {
        // ---------------- agg role: 4 items, ascending-b phases ------------
        for (int it = 0; it < 4; ++it) {
            const int item = blockIdx.x + it * NAGG;   // 0..511, b-ascending
            const int b  = item >> 4;                  // 16 items per b
            const int cg = item & 15;
            const int c  = cg * 4 + w;

            const float* xp = x + ((size_t)(b * TT + c * CHUNK)) * DD + 4 * l;
            f32x4 s0 = {0,0,0,0}, s1 = {0,0,0,0};
            f32x4 q0 = {0,0,0,0}, q1 = {0,0,0,0};
            f32x4 m0 = {0,0,0,0}, m1 = {0,0,0,0};
            #pragma unroll 4
            for (int k = 0; k < CHUNK; ++k) {
                f32x4 a  = *(const f32x4*)(xp + (size_t)k * DD);
                f32x4 b2 = *(const f32x4*)(xp + (size_t)k * DD + 256);
                s0 += a;  q0 += a * a;   m0 = vmax4(m0, a);
                s1 += b2; q1 += b2 * b2; m1 = vmax4(m1, b2);
            }
            const size_t o = (size_t)c * 4096 + (size_t)b * 128 + l;
            aS[o]       = s0;  aS[o + 64]  = s1;
            aM2[o]      = q0 - s0 * s0 * icf;
            aM2[o + 64] = q1 - s1 * s1 * icf;
            aMX[o]      = m0;  aMX[o + 64] = m1;

            __threadfence();        // device-scope release of my stores
            __syncthreads();        // all threads' fences precede the add
            if (tid == 0) {
                __hip_atomic_fetch_add(&cnt[b], 1, __ATOMIC_RELEASE,
                                       __HIP_MEMORY_SCOPE_AGENT);
            }
            __syncthreads();
        }
        return;
    }

    // ---------------- scan role: (b, g, h), 4 waves = 4 chunks -------------
    const int sidx = blockIdx.x - NAGG;        // 0..1023
    const int h    = sidx & 1;
    const int g    = (sidx >> 1) & (GRP - 1);
    const int b    = sidx >> 5;                // 32 b's
    const int c0   = g * 4;
    const int c    = c0 + w;
    const int hofs = 64 * h;

    // wait for all 16 agg items of my b (coarse: one spin per block)
    if (tid == 0) {
        while (__hip_atomic_load(&cnt[b], __ATOMIC_RELAXED,
                                 __HIP_MEMORY_SCOPE_AGENT) < 16) {
            __builtin_amdgcn_s_sleep(2);
        }
    }
    __syncthreads();
    __builtin_amdgcn_fence(__ATOMIC_ACQUIRE, "agent");

    // cooperative fold of shared prefix [0, c0): wave w folds quarter
    St1 q; st1_zero(q);
    for (int j = w * g; j < (w + 1) * g; ++j) {
        const size_t oj = (size_t)j * 4096 + (size_t)b * 128 + l + hofs;
        st1_merge(q, (float)CHUNK, icf, aS[oj], aM2[oj], aMX[oj]);
    }
    part[w][0][l] = q.s; part[w][1][l] = q.m2; part[w][2][l] = q.mx;
    __syncthreads();

    St1 r; st1_zero(r);
    if (g > 0) {
        const float qn  = (float)(g * CHUNK);
        const float iqn = fast_rcp(qn);
        #pragma unroll
        for (int qq = 0; qq < 4; ++qq) {
            st1_merge(r, qn, iqn, part[qq][0][l], part[qq][1][l], part[qq][2][l]);
        }
    }
    for (int j = c0; j < c; ++j) {
        const size_t oj = (size_t)j * 4096 + (size_t)b * 128 + l + hofs;
        st1_merge(r, (float)CHUNK, icf, aS[oj], aM2[oj], aMX[oj]);
    }

    float cnt2 = r.n;  // == c * CHUNK
    f32x4 rs = r.s, rm2 = r.m2, rmx = r.mx;
    f32x4 rmean = {0,0,0,0};
    if (c > 0) rmean = rs * fast_rcp(cnt2);

    const float* xp = x   + ((size_t)(b * TT + c * CHUNK)) * DD + h * 256 + 4 * l;
    float*       op = out + ((size_t)(b * TT + c * CHUNK)) * (3 * DD) + h * 256 + 4 * l;

    #pragma unroll 4
    for (int k = 0; k < CHUNK; ++k) {
        f32x4 v = *(const f32x4*)(xp + (size_t)k * DD);
        cnt2 += 1.f;
        float inv = fast_rcp(cnt2);
        rs += v;
        rmx = vmax4(rmx, v);
        f32x4 nm = rs * inv;
        rm2 += (v - rmean) * (v - nm);
        rmean = nm;
        f32x4 var = rm2 * inv;
        float* row = op + (size_t)k * (3 * DD);
        nts(nm,  row);
        nts(var, row + 512);
        nts(rmx, row + 1024);
    }
}

// ================= R11 fallback path (proven 118.7us) =====================
template <int NC>
__launch_bounds__(256)
__global__ void dmv_agg_kernel(const float* __restrict__ x,
                               f32x4* __restrict__ ws4) {
    constexpr int CHUNK = TT / NC;
    f32x4* __restrict__ aS  = ws4;
    f32x4* __restrict__ aM2 = ws4 + (size_t)NC * 4096;
    f32x4* __restrict__ aMX = ws4 + 2 * (size_t)NC * 4096;

    const int tid = blockIdx.x * 256 + threadIdx.x;
    const int W   = tid >> 6;
    const int l   = tid & 63;
    const int c   = W & (NC - 1);
    const int b   = W / NC;

    const float* xp = x + ((size_t)(b * TT + c * CHUNK)) * DD + 4 * l;

    f32x4 s0 = {0,0,0,0}, s1 = {0,0,0,0};
    f32x4 q0 = {0,0,0,0}, q1 = {0,0,0,0};
    f32x4 m0 = {0,0,0,0}, m1 = {0,0,0,0};
    #pragma unroll 4
    for (int k = 0; k < CHUNK; ++k) {
        f32x4 a  = *(const f32x4*)(xp + (size_t)k * DD);
        f32x4 b2 = *(const f32x4*)(xp + (size_t)k * DD + 256);
        s0 += a;  q0 += a * a;   m0 = vmax4(m0, a);
        s1 += b2; q1 += b2 * b2; m1 = vmax4(m1, b2);
    }
    const size_t o = (size_t)c * 4096 + (size_t)b * 128 + l;
    const float ic = 1.0f / (float)CHUNK;
    aS[o]       = s0;  aS[o + 64]  = s1;
    aM2[o]      = q0 - s0 * s0 * ic;
    aM2[o + 64] = q1 - s1 * s1 * ic;
    aMX[o]      = m0;  aMX[o + 64] = m1;
}

template <int NC>
__launch_bounds__(512)
__global__ void dmv_scan_split(const float* __restrict__ x,
                               const f32x4* __restrict__ ws4,
                               float* __restrict__ out) {
    constexpr int CHUNK = TT / NC;
    constexpr int GRP   = NC / 4;
    const f32x4* __restrict__ aS  = ws4;
    const f32x4* __restrict__ aM2 = ws4 + (size_t)NC * 4096;
    const f32x4* __restrict__ aMX = ws4 + 2 * (size_t)NC * 4096;

    __shared__ f32x4 part[8][3][64];

    const int tid = threadIdx.x;
    const int w   = tid >> 6;
    const int l   = tid & 63;
    const int h   = w & 1;
    const int cw  = w >> 1;
    const int g   = blockIdx.x & (GRP - 1);
    const int b   = blockIdx.x / GRP;
    const int c0  = g * 4;
    const int c   = c0 + cw;

    constexpr float icf = 1.0f / (float)CHUNK;
    const int hofs = 64 * h;

    St1 q; st1_zero(q);
    for (int j = cw * g; j < (cw + 1) * g; ++j) {
        const size_t oj = (size_t)j * 4096 + (size_t)b * 128 + l + hofs;
        st1_merge(q, (float)CHUNK, icf, aS[oj], aM2[oj], aMX[oj]);
    }
    part[w][0][l] = q.s; part[w][1][l] = q.m2; part[w][2][l] = q.mx;
    __syncthreads();

    St1 r; st1_zero(r);
    if (g > 0) {
        const float qn  = (float)(g * CHUNK);
        const float iqn = fast_rcp(qn);
        #pragma unroll
        for (int qq = 0; qq < 4; ++qq) {
            const int pw = 2 * qq + h;
            st1_merge(r, qn, iqn, part[pw][0][l], part[pw][1][l], part[pw][2][l]);
        }
    }
    for (int j = c0; j < c; ++j) {
        const size_t oj = (size_t)j * 4096 + (size_t)b * 128 + l + hofs;
        st1_merge(r, (float)CHUNK, icf, aS[oj], aM2[oj], aMX[oj]);
    }

    float cnt = r.n;
    f32x4 rs = r.s, rm2 = r.m2, rmx = r.mx;
    f32x4 rmean = {0,0,0,0};
    if (c > 0) rmean = rs * fast_rcp(cnt);

    const float* xp = x   + ((size_t)(b * TT + c * CHUNK)) * DD + h * 256 + 4 * l;
    float*       op = out + ((size_t)(b * TT + c * CHUNK)) * (3 * DD) + h * 256 + 4 * l;

    #pragma unroll 4
    for (int k = 0; k < CHUNK; ++k) {
        f32x4 v = *(const f32x4*)(xp + (size_t)k * DD);
        cnt += 1.f;
        float inv = fast_rcp(cnt);
        rs += v;
        rmx = vmax4(rmx, v);
        f32x4 nm = rs * inv;
        rm2 += (v - rmean) * (v - nm);
        rmean = nm;
        f32x4 var = rm2 * inv;
        float* row = op + (size_t)k * (3 * DD);
        nts(nm,  row);
        nts(var, row + 512);
        nts(rmx, row + 1024);
    }
}

#define FNW 16
#define FCHUNK (TT / FNW)
#define DGRP 64

__launch_bounds__(1024, 1)
__global__ void dmv_scan_fallback(const float* __restrict__ x,
                                  float* __restrict__ out) {
    __shared__ float aggS[FNW][DGRP];
    __shared__ float aggM2[FNW][DGRP];
    __shared__ float aggMX[FNW][DGRP];

    const int tid = threadIdx.x;
    const int w   = tid >> 6;
    const int l   = tid & 63;
    const int b   = blockIdx.x >> 3;
    const int d0  = (blockIdx.x & 7) * DGRP;

    const float* xp = x   + ((size_t)b * TT) * DD + d0 + l
                          + (size_t)(w * FCHUNK) * DD;
    float*       op = out + ((size_t)b * TT) * (3 * DD) + d0 + l
                          + (size_t)(w * FCHUNK) * (3 * DD);

    if (w < FNW - 1) {
        float s = 0.f, ss = 0.f, mx = 0.f;
        #pragma unroll 8
        for (int k = 0; k < FCHUNK; ++k) {
            float xv = xp[(size_t)k * DD];
            s += xv; ss = fmaf(xv, xv, ss); mx = fmaxf(mx, xv);
        }
        aggS[w][l] = s;
        aggM2[w][l] = ss - s * s * (1.0f / FCHUNK);
        aggMX[w][l] = mx;
    }
    __syncthreads();

    float c_n = 0.f, c_s = 0.f, c_m2 = 0.f, c_mx = 0.f;
    for (int j = 0; j < w; ++j) {
        float bs = aggS[j][l], bm2 = aggM2[j][l], bmx = aggMX[j][l];
        if (j == 0) {
            c_n = (float)FCHUNK; c_s = bs; c_m2 = bm2; c_mx = bmx;
        } else {
            float n  = c_n + (float)FCHUNK;
            float da = bs * (1.0f / FCHUNK) - c_s / c_n;
            c_m2 = c_m2 + bm2 + da * da * (c_n * (float)FCHUNK / n);
            c_s += bs; c_mx = fmaxf(c_mx, bmx); c_n = n;
        }
    }

    float cnt = c_n, rs = c_s, rm2 = c_m2, rmx = c_mx;
    float rmean = (w > 0) ? rs / cnt : 0.f;
    #pragma unroll 8
    for (int k = 0; k < FCHUNK; ++k) {
        float xv = xp[(size_t)k * DD];
        cnt += 1.f;
        float inv = fast_rcp(cnt);
        rs += xv; rmx = fmaxf(rmx, xv);
        float nm = rs * inv;
        rm2 += (xv - rmean) * (xv - nm);
        rmean = nm;
        float var = rm2 * inv;
        float* orow = op + (size_t)k * (3 * DD);
        orow[0] = nm; orow[DD] = var; orow[2 * DD] = rmx;
    }
}

// ---------------- launchers ----------------
template <int NC>
static void launch_2k(const float* x, float* out, void* d_ws, hipStream_t stream) {
    dmv_agg_kernel<NC><<<dim3(8 * NC), dim3(256), 0, stream>>>(x, (f32x4*)d_ws);
    dmv_scan_split<NC><<<dim3(8 * NC), dim3(512), 0, stream>>>(
        x, (const f32x4*)d_ws, out);
}

extern "C" void kernel_launch(void* const* d_in, const int* in_sizes, int n_in,
                              void* d_out, int out_size, void* d_ws, size_t ws_size,
                              hipStream_t stream) {
    (void)in_sizes; (void)n_in; (void)out_size;
    const float* x = (const float*)d_in[0];
    float* out = (float*)d_out;

    const size_t tabBytes = (size_t)3 * 64 * 4096 * sizeof(f32x4);  // 12.6 MB
    const size_t needF    = tabBytes + 128;
    const size_t need64   = tabBytes;
    const size_t need32   = (size_t)3 * 32 * 4096 * sizeof(f32x4);

    if (d_ws && ws_size >= needF) {
        f32x4* ws4 = (f32x4*)d_ws;
        int* cnt = (int*)((char*)d_ws + tabBytes);
        hipMemsetAsync(cnt, 0, BB * sizeof(int), stream);
        void* kargs[] = {(void*)&x, (void*)&ws4, (void*)&cnt, (void*)&out};
        hipError_t e = hipLaunchCooperativeKernel(
            (const void*)dmv_fused<64>, dim3(NAGG + 1024), dim3(256),
            kargs, 0, stream);
        if (e != hipSuccess) {
            launch_2k<64>(x, out, d_ws, stream);  // proven R11 path
        }
    } else if (d_ws && ws_size >= need64) {
        launch_2k<64>(x, out, d_ws, stream);
    } else if (d_ws && ws_size >= need32) {
        launch_2k<32>(x, out, d_ws, stream);
    } else {
        dmv_scan_fallback<<<dim3(BB * (DD / DGRP)), dim3(1024), 0, stream>>>(x, out);
    }
}

// Round 13
// 119.110 us; speedup vs baseline: 2.1512x; 2.1512x over previous
//
#include <hip/hip_runtime.h>

// DmvCell RNN scan, B=32, T=2048, D=512. out[b][t] = [mean|var|max] (3*D).
// Compulsory: 128 MB in + 402 MB nt-out.
// FINAL STRUCTURE (R11, 118.7us): 2-kernel agg->scan, nt stores + regular
// loads, cooperative LDS fold, D-split scan waves.
// Falsified levers: fine lookback (R7: +58us), coarse coop handoff (R12:
// +137us), NC=128 (R9: +41us), reg stores (R5: +25us), nt loads (R10:
// +44us), occupancy (R2/R9/R11: <2us), fold traffic (R8: ~0), rw batching
// (R8: ~0). Kernel-boundary barrier beats every in-kernel global sync.

#define BB 32
#define TT 2048
#define DD 512
#define NCHAIN (BB * DD)

typedef float f32x4 __attribute__((ext_vector_type(4)));

__device__ __forceinline__ float fast_rcp(float x) {
#if __has_builtin(__builtin_amdgcn_rcpf)
    return __builtin_amdgcn_rcpf(x);
#else
    return 1.0f / x;
#endif
}

__device__ __forceinline__ f32x4 vmax4(f32x4 a, f32x4 b) {
#if __has_builtin(__builtin_elementwise_max)
    return __builtin_elementwise_max(a, b);
#else
    f32x4 r;
    r.x = fmaxf(a.x, b.x); r.y = fmaxf(a.y, b.y);
    r.z = fmaxf(a.z, b.z); r.w = fmaxf(a.w, b.w);
    return r;
#endif
}

__device__ __forceinline__ void nts(f32x4 v, float* p) {
#if __has_builtin(__builtin_nontemporal_store)
    __builtin_nontemporal_store(v, (f32x4*)p);
#else
    *(f32x4*)p = v;
#endif
}

// Half-row Welford state: 4 chains (1 f32x4) per lane.
struct St1 {
    float n;
    f32x4 s, m2, mx;
};

__device__ __forceinline__ void st1_zero(St1& r) {
    r.n = 0.f;
    r.s = r.m2 = r.mx = (f32x4){0.f, 0.f, 0.f, 0.f};
}

// merge block (tn, ts, tm, tx) into r; tn > 0. Ascending-order folds only.
__device__ __forceinline__ void st1_merge(St1& r, float tn, float itn,
                                          f32x4 ts, f32x4 tm, f32x4 tx) {
    if (r.n == 0.f) {   // uniform per wave
        r.n = tn; r.s = ts; r.m2 = tm; r.mx = tx;
    } else {
        float n     = r.n + tn;
        float irn   = fast_rcp(r.n);
        float scale = r.n * tn * fast_rcp(n);
        f32x4 da = ts * itn - r.s * irn;
        r.m2 += tm + da * da * scale;
        r.s += ts;
        r.mx = vmax4(r.mx, tx);
        r.n = n;
    }
}

// ---------------- kernel 1: per-chunk aggregates ---------------------------
template <int NC>
__launch_bounds__(256)
__global__ void dmv_agg_kernel(const float* __restrict__ x,
                               f32x4* __restrict__ ws4) {
    constexpr int CHUNK = TT / NC;
    f32x4* __restrict__ aS  = ws4;
    f32x4* __restrict__ aM2 = ws4 + (size_t)NC * 4096;
    f32x4* __restrict__ aMX = ws4 + 2 * (size_t)NC * 4096;

    const int tid = blockIdx.x * 256 + threadIdx.x;
    const int W   = tid >> 6;
    const int l   = tid & 63;
    const int c   = W & (NC - 1);
    const int b   = W / NC;

    const float* xp = x + ((size_t)(b * TT + c * CHUNK)) * DD + 4 * l;

    f32x4 s0 = {0,0,0,0}, s1 = {0,0,0,0};
    f32x4 q0 = {0,0,0,0}, q1 = {0,0,0,0};
    f32x4 m0 = {0,0,0,0}, m1 = {0,0,0,0};
    #pragma unroll 4
    for (int k = 0; k < CHUNK; ++k) {
        f32x4 a  = *(const f32x4*)(xp + (size_t)k * DD);
        f32x4 b2 = *(const f32x4*)(xp + (size_t)k * DD + 256);
        s0 += a;  q0 += a * a;   m0 = vmax4(m0, a);
        s1 += b2; q1 += b2 * b2; m1 = vmax4(m1, b2);
    }
    const size_t o = (size_t)c * 4096 + (size_t)b * 128 + l;
    const float ic = 1.0f / (float)CHUNK;
    aS[o]       = s0;  aS[o + 64]  = s1;
    aM2[o]      = q0 - s0 * s0 * ic;
    aM2[o + 64] = q1 - s1 * s1 * ic;
    aMX[o]      = m0;  aMX[o + 64] = m1;
}

// -------- kernel 2: D-split coop fold + rescan + nt stores -----------------
// 512 threads = 8 waves = 4 chunks x 2 D-halves. wave w: chunk cw=w>>1,
// half h=w&1. Same merge tree per half (halves are independent chains).
template <int NC>
__launch_bounds__(512)
__global__ void dmv_scan_split(const float* __restrict__ x,
                               const f32x4* __restrict__ ws4,
                               float* __restrict__ out) {
    constexpr int CHUNK = TT / NC;
    constexpr int GRP   = NC / 4;          // blocks per batch b
    const f32x4* __restrict__ aS  = ws4;
    const f32x4* __restrict__ aM2 = ws4 + (size_t)NC * 4096;
    const f32x4* __restrict__ aMX = ws4 + 2 * (size_t)NC * 4096;

    __shared__ f32x4 part[8][3][64];       // [wave][{s,m2,mx}][lane]

    const int tid = threadIdx.x;
    const int w   = tid >> 6;              // 0..7
    const int l   = tid & 63;
    const int h   = w & 1;                 // D-half
    const int cw  = w >> 1;                // chunk within block (0..3)
    const int g   = blockIdx.x & (GRP - 1);
    const int b   = blockIdx.x / GRP;
    const int c0  = g * 4;
    const int c   = c0 + cw;

    constexpr float icf = 1.0f / (float)CHUNK;
    const int hofs = 64 * h;               // table offset for my half

    // ---- cooperative fold of shared prefix [0, c0): wave (cw,h) folds
    //      quarter [cw*g, (cw+1)*g) of half h ----
    St1 q; st1_zero(q);
    for (int j = cw * g; j < (cw + 1) * g; ++j) {
        const size_t oj = (size_t)j * 4096 + (size_t)b * 128 + l + hofs;
        st1_merge(q, (float)CHUNK, icf, aS[oj], aM2[oj], aMX[oj]);
    }
    part[w][0][l] = q.s; part[w][1][l] = q.m2; part[w][2][l] = q.mx;
    __syncthreads();

    // ---- my exclusive prefix: partials of my half in ascending chunk
    //      order (waves 2*qq+h), then intra-block chunks c0..c-1 ----
    St1 r; st1_zero(r);
    if (g > 0) {
        const float qn  = (float)(g * CHUNK);
        const float iqn = fast_rcp(qn);
        #pragma unroll
        for (int qq = 0; qq < 4; ++qq) {
            const int pw = 2 * qq + h;
            st1_merge(r, qn, iqn, part[pw][0][l], part[pw][1][l], part[pw][2][l]);
        }
    }
    for (int j = c0; j < c; ++j) {
        const size_t oj = (size_t)j * 4096 + (size_t)b * 128 + l + hofs;
        st1_merge(r, (float)CHUNK, icf, aS[oj], aM2[oj], aMX[oj]);
    }

    float cnt = r.n;  // == c * CHUNK
    f32x4 rs = r.s, rm2 = r.m2, rmx = r.mx;
    f32x4 rmean = {0,0,0,0};
    if (c > 0) rmean = rs * fast_rcp(cnt);

    // ---- exact sequential rescan of own (chunk, half); nt stores ----
    const float* xp = x   + ((size_t)(b * TT + c * CHUNK)) * DD + h * 256 + 4 * l;
    float*       op = out + ((size_t)(b * TT + c * CHUNK)) * (3 * DD) + h * 256 + 4 * l;

    #pragma unroll 4
    for (int k = 0; k < CHUNK; ++k) {
        f32x4 v = *(const f32x4*)(xp + (size_t)k * DD);
        cnt += 1.f;
        float inv = fast_rcp(cnt);
        rs += v;
        rmx = vmax4(rmx, v);
        f32x4 nm = rs * inv;
        rm2 += (v - rmean) * (v - nm);
        rmean = nm;
        f32x4 var = rm2 * inv;
        float* row = op + (size_t)k * (3 * DD);
        nts(nm,  row);
        nts(var, row + 512);
        nts(rmx, row + 1024);
    }
}

// ---------------- fallback (R2, proven): single kernel, LDS merge ----------
#define FNW 16
#define FCHUNK (TT / FNW)
#define DGRP 64

__launch_bounds__(1024, 1)
__global__ void dmv_scan_fallback(const float* __restrict__ x,
                                  float* __restrict__ out) {
    __shared__ float aggS[FNW][DGRP];
    __shared__ float aggM2[FNW][DGRP];
    __shared__ float aggMX[FNW][DGRP];

    const int tid = threadIdx.x;
    const int w   = tid >> 6;
    const int l   = tid & 63;
    const int b   = blockIdx.x >> 3;
    const int d0  = (blockIdx.x & 7) * DGRP;

    const float* xp = x   + ((size_t)b * TT) * DD + d0 + l
                          + (size_t)(w * FCHUNK) * DD;
    float*       op = out + ((size_t)b * TT) * (3 * DD) + d0 + l
                          + (size_t)(w * FCHUNK) * (3 * DD);

    if (w < FNW - 1) {
        float s = 0.f, ss = 0.f, mx = 0.f;
        #pragma unroll 8
        for (int k = 0; k < FCHUNK; ++k) {
            float xv = xp[(size_t)k * DD];
            s += xv; ss = fmaf(xv, xv, ss); mx = fmaxf(mx, xv);
        }
        aggS[w][l] = s;
        aggM2[w][l] = ss - s * s * (1.0f / FCHUNK);
        aggMX[w][l] = mx;
    }
    __syncthreads();

    float c_n = 0.f, c_s = 0.f, c_m2 = 0.f, c_mx = 0.f;
    for (int j = 0; j < w; ++j) {
        float bs = aggS[j][l], bm2 = aggM2[j][l], bmx = aggMX[j][l];
        if (j == 0) {
            c_n = (float)FCHUNK; c_s = bs; c_m2 = bm2; c_mx = bmx;
        } else {
            float n  = c_n + (float)FCHUNK;
            float da = bs * (1.0f / FCHUNK) - c_s / c_n;
            c_m2 = c_m2 + bm2 + da * da * (c_n * (float)FCHUNK / n);
            c_s += bs; c_mx = fmaxf(c_mx, bmx); c_n = n;
        }
    }

    float cnt = c_n, rs = c_s, rm2 = c_m2, rmx = c_mx;
    float rmean = (w > 0) ? rs / cnt : 0.f;
    #pragma unroll 8
    for (int k = 0; k < FCHUNK; ++k) {
        float xv = xp[(size_t)k * DD];
        cnt += 1.f;
        float inv = fast_rcp(cnt);
        rs += xv; rmx = fmaxf(rmx, xv);
        float nm = rs * inv;
        rm2 += (xv - rmean) * (xv - nm);
        rmean = nm;
        float var = rm2 * inv;
        float* orow = op + (size_t)k * (3 * DD);
        orow[0] = nm; orow[DD] = var; orow[2 * DD] = rmx;
    }
}

// ---------------- launcher ----------------
template <int NC>
static void launch_2k(const float* x, float* out, void* d_ws, hipStream_t stream) {
    dmv_agg_kernel<NC><<<dim3(8 * NC), dim3(256), 0, stream>>>(x, (f32x4*)d_ws);
    dmv_scan_split<NC><<<dim3(8 * NC), dim3(512), 0, stream>>>(
        x, (const f32x4*)d_ws, out);
}

extern "C" void kernel_launch(void* const* d_in, const int* in_sizes, int n_in,
                              void* d_out, int out_size, void* d_ws, size_t ws_size,
                              hipStream_t stream) {
    (void)in_sizes; (void)n_in; (void)out_size;
    const float* x = (const float*)d_in[0];
    float* out = (float*)d_out;

    const size_t need64 = (size_t)3 * 64 * 4096 * sizeof(f32x4);  // 12.6 MB
    const size_t need32 = (size_t)3 * 32 * 4096 * sizeof(f32x4);  //  6.3 MB

    if (d_ws && ws_size >= need64) {
        launch_2k<64>(x, out, d_ws, stream);
    } else if (d_ws && ws_size >= need32) {
        launch_2k<32>(x, out, d_ws, stream);
    } else {
        dmv_scan_fallback<<<dim3(BB * (DD / DGRP)), dim3(1024), 0, stream>>>(x, out);
    }
}